// Round 7
// baseline (594.669 us; speedup 1.0000x reference)
//
#include <hip/hip_runtime.h>
#include <hip/hip_bf16.h>
#include <math.h>

#define SS 2048
#define HH 16
#define EPSF 1e-6f
#define MR 4096              // tokens
#define L2T 13.287712379549449f   // log2(10000)
// 1/sqrt(192) * log2(e), folded into q at the uq-GEMM epilogue
#define ASCL (0.07216878364870322f * 1.4426950408889634f)

typedef unsigned short u16;
typedef unsigned int u32;
typedef __attribute__((ext_vector_type(8))) short bf8_t;
typedef __attribute__((ext_vector_type(4))) float f4_t;

__device__ inline u16 f2b(float f) {
    __hip_bfloat16 h = __float2bfloat16(f);
    return __builtin_bit_cast(u16, h);
}
__device__ inline float b2f(u16 x) {
    u32 v = (u32)x << 16;
    return __builtin_bit_cast(float, v);
}

#define GLD16(g, l) __builtin_amdgcn_global_load_lds( \
    (const __attribute__((address_space(1))) u32*)(g), \
    (__attribute__((address_space(3))) u32*)(l), 16, 0, 0)

#define MFMA16(a,b,c) __builtin_amdgcn_mfma_f32_16x16x32_bf16((a),(b),(c),0,0,0)

// ================= prep: x->bf16 cvt + all 5 weight transposes =================
__global__ void prep_k(const float* __restrict__ x, u16* __restrict__ xb,
                       const float* __restrict__ w_dq, const float* __restrict__ w_dkv,
                       const float* __restrict__ w_uq, const float* __restrict__ w_ukv,
                       const float* __restrict__ w_o,
                       u16* __restrict__ wT1, u16* __restrict__ wTuq,
                       u16* __restrict__ wTukv, u16* __restrict__ wTo) {
    __shared__ float tt[32][33];
    int blk = blockIdx.x, tid = threadIdx.x;
    if (blk < 8192) {                       // x conversion: 4096x2048 fp32 -> bf16
        int i = blk * 256 + tid;
        float4 v = ((const float4*)x)[i];
        ushort4 o;
        o.x = f2b(v.x); o.y = f2b(v.y); o.z = f2b(v.z); o.w = f2b(v.w);
        *(ushort4*)(xb + (size_t)i * 4) = o;
        return;
    }
    blk -= 8192;
    const float* W; u16* dst; int K, N, Npad, nx;
    if (blk < 3072)       { W = w_dq;  dst = wT1;                      K = 2048; N = 1536; Npad = 1536; nx = 48; }
    else if (blk < 4352)  { blk -= 3072; W = w_dkv; dst = wT1 + (size_t)1536 * 2048; K = 2048; N = 576;  Npad = 640;  nx = 20; }
    else if (blk < 8960)  { blk -= 4352; W = w_uq;  dst = wTuq;        K = 1536; N = 3072; Npad = 3072; nx = 96; }
    else if (blk < 11008) { blk -= 8960; W = w_ukv; dst = wTukv;       K = 512;  N = 4096; Npad = 4096; nx = 128; }
    else                  { blk -= 11008; W = w_o;  dst = wTo;         K = 2048; N = 2048; Npad = 2048; nx = 64; }
    int n0 = (blk % nx) * 32, k0 = (blk / nx) * 32;
    int tx = tid & 31, ty = tid >> 5;
    for (int i = ty; i < 32; i += 8) {
        int n = n0 + tx;
        tt[i][tx] = (n < N) ? W[(size_t)(k0 + i) * N + n] : 0.f;
    }
    __syncthreads();
    for (int i = ty; i < 32; i += 8) {
        int n = n0 + i;
        if (n < Npad) dst[(size_t)n * K + k0 + tx] = f2b(tt[tx][i]);
    }
}

// ================= MFMA GEMM (m97 structure), templated epilogue =================
// MODE 0: fp32 out; MODE 1: bf16 out; MODE 2: bf16 + fused RoPE + ASCL (q path);
// MODE 3: kv path -> k_nope into kb[tok][16][192], V transposed into vT[16][128][4096]
//         (even n-blocks are pure k_nope, odd are pure V; V goes through an LDS
//          transpose so global stores are 128B-coalesced along tok)
template <int MODE, int MINW>
__global__ __launch_bounds__(256, MINW)
void gemm_mfma(const u16* __restrict__ A, const u16* __restrict__ BT,
               void* __restrict__ Cv, void* __restrict__ Cv2, int K, int N) {
    __shared__ u16 lA[128 * 32];
    __shared__ u16 lB[128 * 32];
    const int tid = threadIdx.x;
    const int w = tid >> 6, lane = tid & 63;
    const int quad = lane >> 4, col = lane & 15;
    const int wm = (w >> 1) * 64, wn = (w & 1) * 64;
    const int bm = blockIdx.y * 128, bn = blockIdx.x * 128;
    const int srow = lane >> 2;
    const int scol = (lane & 3) * 8;
    f4_t acc[4][4] = {};
    for (int k0 = 0; k0 < K; k0 += 32) {
        __syncthreads();
        #pragma unroll
        for (int cc = 0; cc < 2; cc++) {
            int c = 2 * w + cc;
            int row = c * 16 + srow;
            GLD16(A  + (size_t)(bm + row) * K + k0 + scol, (char*)lA + c * 1024);
            GLD16(BT + (size_t)(bn + row) * K + k0 + scol, (char*)lB + c * 1024);
        }
        __syncthreads();
        bf8_t af[4], bf[4];
        #pragma unroll
        for (int i = 0; i < 4; i++) {
            af[i] = *(const bf8_t*)(lA + (wm + i * 16 + col) * 32 + quad * 8);
            bf[i] = *(const bf8_t*)(lB + (wn + i * 16 + col) * 32 + quad * 8);
        }
        #pragma unroll
        for (int mi = 0; mi < 4; mi++)
            #pragma unroll
            for (int ni = 0; ni < 4; ni++)
                acc[mi][ni] = MFMA16(af[mi], bf[ni], acc[mi][ni]);
    }
    if constexpr (MODE == 0) {
        float* C = (float*)Cv;
        #pragma unroll
        for (int mi = 0; mi < 4; mi++)
            #pragma unroll
            for (int ni = 0; ni < 4; ni++) {
                int n = bn + wn + ni * 16 + col;
                #pragma unroll
                for (int r = 0; r < 4; r++) {
                    int m = bm + wm + mi * 16 + quad * 4 + r;
                    C[(size_t)m * N + n] = acc[mi][ni][r];
                }
            }
    } else if constexpr (MODE == 1) {
        u16* C = (u16*)Cv;
        #pragma unroll
        for (int mi = 0; mi < 4; mi++)
            #pragma unroll
            for (int ni = 0; ni < 4; ni++) {
                int n = bn + wn + ni * 16 + col;
                #pragma unroll
                for (int r = 0; r < 4; r++) {
                    int m = bm + wm + mi * 16 + quad * 4 + r;
                    C[(size_t)m * N + n] = f2b(acc[mi][ni][r]);
                }
            }
    } else if constexpr (MODE == 2) {
        u16* C = (u16*)Cv;
        int span = ((bn + wn) >> 6) % 3;      // 0,1: nope span; 2: pe span (64-aligned)
        if (span < 2) {
            #pragma unroll
            for (int mi = 0; mi < 4; mi++)
                #pragma unroll
                for (int ni = 0; ni < 4; ni++) {
                    int n = bn + wn + ni * 16 + col;
                    #pragma unroll
                    for (int r = 0; r < 4; r++) {
                        int m = bm + wm + mi * 16 + quad * 4 + r;
                        C[(size_t)m * N + n] = f2b(acc[mi][ni][r] * ASCL);
                    }
                }
        } else {
            #pragma unroll
            for (int ni = 0; ni < 2; ni++) {
                int e = ni * 16 + col;        // rope dim 0..31
                float inv = exp2f(-(float)e * (L2T / 32.0f));
                #pragma unroll
                for (int mi = 0; mi < 4; mi++) {
                    #pragma unroll
                    for (int r = 0; r < 4; r++) {
                        int m = bm + wm + mi * 16 + quad * 4 + r;
                        int pos = m & (SS - 1);
                        float ang = (float)pos * inv;
                        float cs, sn; sincosf(ang, &sn, &cs);
                        float x1 = acc[mi][ni][r], x2 = acc[mi][ni + 2][r];
                        int n = bn + wn + ni * 16 + col;
                        C[(size_t)m * N + n]      = f2b((x1 * cs - x2 * sn) * ASCL);
                        C[(size_t)m * N + n + 32] = f2b((x2 * cs + x1 * sn) * ASCL);
                    }
                }
            }
        }
    } else { // MODE 3
        u16* kb = (u16*)Cv;
        u16* vT = (u16*)Cv2;
        int h = blockIdx.x >> 1;
        if ((blockIdx.x & 1) == 0) {
            // k_nope block: col index = wn + ni*16 + col (0..127)
            #pragma unroll
            for (int ni = 0; ni < 4; ni++) {
                int cb = wn + ni * 16;
                #pragma unroll
                for (int mi = 0; mi < 4; mi++)
                    #pragma unroll
                    for (int r = 0; r < 4; r++) {
                        int m = bm + wm + mi * 16 + quad * 4 + r;
                        kb[((size_t)m * HH + h) * 192 + cb + col] = f2b(acc[mi][ni][r]);
                    }
            }
        } else {
            // V block: transpose 64x64 per wave in LDS, store coalesced along tok
            __shared__ u16 sc[4][64][72];
            u16 (*scw)[72] = sc[w];
            #pragma unroll
            for (int ni = 0; ni < 4; ni++) {
                int dvl = ni * 16 + col;
                #pragma unroll
                for (int mi = 0; mi < 4; mi++) {
                    ushort4 o;
                    o.x = f2b(acc[mi][ni][0]);
                    o.y = f2b(acc[mi][ni][1]);
                    o.z = f2b(acc[mi][ni][2]);
                    o.w = f2b(acc[mi][ni][3]);
                    *(ushort4*)&scw[dvl][mi * 16 + quad * 4] = o;
                }
            }
            // wave-private: no barrier needed, compiler inserts lgkmcnt waits
            #pragma unroll
            for (int cc = 0; cc < 8; cc++) {
                int dvl = cc * 8 + (lane >> 3);
                int t8 = lane & 7;
                bf8_t vv = *(const bf8_t*)&scw[dvl][t8 * 8];
                *(bf8_t*)(vT + ((size_t)(h * 128 + wn + dvl)) * 4096 + bm + wm + t8 * 8) = vv;
            }
        }
    }
}

// ===== merged rmsnorm: blocks 0..4095 -> q latent; 4096..8191 -> kv latent + rope k_pe =====
__global__ void rms_all_k(const u16* __restrict__ C1, const float* __restrict__ wq,
                          const float* __restrict__ wkv,
                          u16* __restrict__ qlb, u16* __restrict__ ckvnb,
                          u16* __restrict__ kb) {
    __shared__ float red[256];
    int tid = threadIdx.x;
    if (blockIdx.x < 4096) {
        int row = blockIdx.x;
        const ushort4* rp = (const ushort4*)(C1 + (size_t)row * 2176);
        float s = 0.f;
        for (int i = tid; i < 384; i += 256) {
            ushort4 u = rp[i];
            float a = b2f(u.x), b = b2f(u.y), c = b2f(u.z), d = b2f(u.w);
            s += a * a + b * b + c * c + d * d;
        }
        red[tid] = s;
        __syncthreads();
        for (int off = 128; off > 0; off >>= 1) {
            if (tid < off) red[tid] += red[tid + off];
            __syncthreads();
        }
        float sc = rsqrtf(red[0] * (1.0f / 1536.0f) + EPSF);
        ushort4* op = (ushort4*)(qlb + (size_t)row * 1536);
        const float4* wv = (const float4*)wq;
        for (int i = tid; i < 384; i += 256) {
            ushort4 u = rp[i];
            float4 ww = wv[i];
            ushort4 o;
            o.x = f2b(b2f(u.x) * sc * ww.x);
            o.y = f2b(b2f(u.y) * sc * ww.y);
            o.z = f2b(b2f(u.z) * sc * ww.z);
            o.w = f2b(b2f(u.w) * sc * ww.w);
            op[i] = o;
        }
    } else {
        int row = blockIdx.x - 4096;
        const u16* base = C1 + (size_t)row * 2176 + 1536;
        if (tid < 32) {   // rope k_pe -> broadcast into kb[row][h][128..192]
            int t = tid;
            float x1 = b2f(base[512 + t]), x2 = b2f(base[544 + t]);
            int pos = row & (SS - 1);
            float inv = exp2f(-(float)t * (L2T / 32.0f));
            float ang = (float)pos * inv;
            float cs, sn; sincosf(ang, &sn, &cs);
            u16 y1 = f2b(x1 * cs - x2 * sn);
            u16 y2 = f2b(x2 * cs + x1 * sn);
            u16* kr = kb + (size_t)row * HH * 192;
            #pragma unroll
            for (int h = 0; h < HH; h++) {
                kr[h * 192 + 128 + t] = y1;
                kr[h * 192 + 160 + t] = y2;
            }
        }
        const ushort4* rp = (const ushort4*)base;
        float s = 0.f;
        if (tid < 128) {
            ushort4 u = rp[tid];
            float a = b2f(u.x), b = b2f(u.y), c = b2f(u.z), d = b2f(u.w);
            s = a * a + b * b + c * c + d * d;
        }
        red[tid] = s;
        __syncthreads();
        for (int off = 128; off > 0; off >>= 1) {
            if (tid < off) red[tid] += red[tid + off];
            __syncthreads();
        }
        float sc = rsqrtf(red[0] * (1.0f / 512.0f) + EPSF);
        if (tid < 128) {
            ushort4 u = rp[tid];
            float4 ww = ((const float4*)wkv)[tid];
            ushort4 o;
            o.x = f2b(b2f(u.x) * sc * ww.x);
            o.y = f2b(b2f(u.y) * sc * ww.y);
            o.z = f2b(b2f(u.z) * sc * ww.z);
            o.w = f2b(b2f(u.w) * sc * ww.w);
            ((ushort4*)(ckvnb + (size_t)row * 512))[tid] = o;
        }
    }
}

// ================= Fused flash attention (32 q per wave) =================
// grid (32 bh, 16), block 256 = 4 waves. Q-tile 128/block (32 q/wave, 2 m-halves),
// 64 keys/iter. Q pre-scaled by 1/sqrt(192)*log2e. kb [tok][16][192]; vT [16][128][4096].
// K/V staged via GLD16; kf/vf shared across both m-halves -> LDS bytes per q halved.
__global__ __launch_bounds__(256, 2)
void attn_mfma(const u16* __restrict__ qb, const u16* __restrict__ kb,
               const u16* __restrict__ vT, u16* __restrict__ ob) {
    __shared__ u16 lK[64 * 200];     // [key][192+pad], 400B rows: 25 KB
    __shared__ u16 lV[128 * 72];     // V^T [dv][key(64)+pad], 144B rows: 18 KB
    __shared__ u16 lP[4 * 16 * 72];  // per-wave P [16 q][64 key+pad]: 9 KB
    const int tid = threadIdx.x, w = tid >> 6, lane = tid & 63;
    const int quad = lane >> 4, col = lane & 15;
    const int bh = blockIdx.x, b = bh >> 4, h = bh & 15;
    const int y = blockIdx.y;
    const int qt = (y < 8) ? (15 - y) : (y - 8);   // layer1 long + layer2 short per CU
    const int tok0 = b * SS;
    // per-lane staging offsets: chunks c=w+4*jj; c<25 -> K (400B rows), else V (144B rows)
    int goff[11];
    #pragma unroll
    for (int jj = 0; jj < 11; jj++) {
        int c = w + 4 * jj;
        if (c < 25) {
            int o = c * 1024 + lane * 16;
            int row = o / 400, ro = o - row * 400;
            goff[jj] = (ro < 384) ? (row * HH + h) * 192 + (ro >> 1) : 0;
        } else {
            int c2 = c - 25;
            int o = c2 * 1024 + lane * 16;
            int row = o / 144, ro = o - row * 144;
            goff[jj] = (ro < 128) ? (h * 128 + row) * 4096 + (ro >> 1) : 0;
        }
    }
    u16* pw = lP + w * 16 * 72;
    const int qb0 = qt * 128 + w * 32;   // local q base, m=0 half
    const int qb1 = qb0 + 16;            // m=1 half
    bf8_t qf[2][6];
    #pragma unroll
    for (int m = 0; m < 2; m++) {
        int qtok = tok0 + qb0 + m * 16 + col;
        const u16* qp = qb + ((size_t)qtok * HH + h) * 192 + quad * 8;
        #pragma unroll
        for (int kc = 0; kc < 6; kc++) qf[m][kc] = *(const bf8_t*)(qp + kc * 32);
    }
    f4_t o[2][8] = {};
    float mrow[2][4], lrow[2][4];
    #pragma unroll
    for (int m = 0; m < 2; m++)
        #pragma unroll
        for (int r = 0; r < 4; r++) { mrow[m][r] = -1e30f; lrow[m][r] = 0.f; }

    const int nkt = 2 * qt + 2;
    for (int kt = 0; kt < nkt; kt++) {
        const int kt64 = kt * 64;
        size_t kbase = (size_t)(tok0 + kt64) * (HH * 192);
        size_t vbase = (size_t)(tok0 + kt64);
        __syncthreads();
        #pragma unroll
        for (int jj = 0; jj < 11; jj++) {
            int c = w + 4 * jj;
            if (c < 25)      GLD16(kb + kbase + goff[jj], (char*)lK + c * 1024);
            else if (c < 43) GLD16(vT + vbase + goff[jj], (char*)lV + (c - 25) * 1024);
        }
        __syncthreads();    // vmcnt(0) drain: K+V landed
        // S = Q K^T for both m halves; kf shared
        f4_t s[2][4] = {};
        #pragma unroll
        for (int t = 0; t < 4; t++) {
            int kb_l = kt64 + t * 16;
            if (kb_l <= qb1) {
                bool m0 = (kb_l <= qb0);
                #pragma unroll
                for (int kc = 0; kc < 6; kc++) {
                    bf8_t kf = *(const bf8_t*)(lK + (t * 16 + col) * 200 + kc * 32 + quad * 8);
                    s[1][t] = MFMA16(qf[1][kc], kf, s[1][t]);
                    if (m0) s[0][t] = MFMA16(qf[0][kc], kf, s[0][t]);
                }
            }
        }
        if (kt64 <= qb1) {
            // causal mask (wave-uniform tile tests, per-element inside)
            #pragma unroll
            for (int m = 0; m < 2; m++) {
                int qbm = qb0 + m * 16;
                #pragma unroll
                for (int t = 0; t < 4; t++) {
                    int kb_l = kt64 + t * 16;
                    if (kb_l >= qbm) {
                        int kg = kb_l + col;
                        #pragma unroll
                        for (int r = 0; r < 4; r++)
                            if (kg > qbm + quad * 4 + r) s[m][t][r] = -1e30f;
                    }
                }
            }
            // V fragments once, reused by both m halves
            bf8_t vf[2][8];
            #pragma unroll
            for (int kc2 = 0; kc2 < 2; kc2++)
                #pragma unroll
                for (int n = 0; n < 8; n++)
                    vf[kc2][n] = *(const bf8_t*)(lV + (n * 16 + col) * 72 + kc2 * 32 + quad * 8);
            #pragma unroll
            for (int m = 0; m < 2; m++) {
                if (kt64 <= qb0 + m * 16) {
                    float sm[4] = {-1e30f, -1e30f, -1e30f, -1e30f};
                    #pragma unroll
                    for (int t = 0; t < 4; t++)
                        #pragma unroll
                        for (int r = 0; r < 4; r++) sm[r] = fmaxf(sm[r], s[m][t][r]);
                    #pragma unroll
                    for (int off = 1; off < 16; off <<= 1)
                        #pragma unroll
                        for (int r = 0; r < 4; r++) sm[r] = fmaxf(sm[r], __shfl_xor(sm[r], off));
                    float al[4];
                    #pragma unroll
                    for (int r = 0; r < 4; r++) {
                        float mn = fmaxf(mrow[m][r], sm[r]);
                        al[r] = exp2f(mrow[m][r] - mn);
                        mrow[m][r] = mn;
                    }
                    float rs[4] = {0.f, 0.f, 0.f, 0.f};
                    #pragma unroll
                    for (int t = 0; t < 4; t++)
                        #pragma unroll
                        for (int r = 0; r < 4; r++) {
                            float p = exp2f(s[m][t][r] - mrow[m][r]);
                            s[m][t][r] = p;
                            rs[r] += p;
                        }
                    #pragma unroll
                    for (int off = 1; off < 16; off <<= 1)
                        #pragma unroll
                        for (int r = 0; r < 4; r++) rs[r] += __shfl_xor(rs[r], off);
                    #pragma unroll
                    for (int r = 0; r < 4; r++) lrow[m][r] = lrow[m][r] * al[r] + rs[r];
                    #pragma unroll
                    for (int n = 0; n < 8; n++)
                        #pragma unroll
                        for (int r = 0; r < 4; r++) o[m][n][r] *= al[r];
                    // P (C-layout) -> wave-private LDS
                    #pragma unroll
                    for (int t = 0; t < 4; t++)
                        #pragma unroll
                        for (int r = 0; r < 4; r++)
                            pw[(quad * 4 + r) * 72 + t * 16 + col] = f2b(s[m][t][r]);
                    // O[m] += P V
                    #pragma unroll
                    for (int kc2 = 0; kc2 < 2; kc2++) {
                        bf8_t pf = *(const bf8_t*)(pw + col * 72 + kc2 * 32 + quad * 8);
                        #pragma unroll
                        for (int n = 0; n < 8; n++)
                            o[m][n] = MFMA16(pf, vf[kc2][n], o[m][n]);
                    }
                }
            }
        }
    }
    #pragma unroll
    for (int m = 0; m < 2; m++)
        #pragma unroll
        for (int n = 0; n < 8; n++)
            #pragma unroll
            for (int r = 0; r < 4; r++) {
                int qtok = tok0 + qb0 + m * 16 + quad * 4 + r;
                ob[((size_t)qtok * HH + h) * 128 + n * 16 + col] = f2b(o[m][n][r] / lrow[m][r]);
            }
}

extern "C" void kernel_launch(void* const* d_in, const int* in_sizes, int n_in,
                              void* d_out, int out_size, void* d_ws, size_t ws_size,
                              hipStream_t stream) {
    const float* x        = (const float*)d_in[0];
    const float* w_dq     = (const float*)d_in[1];
    const float* q_a_norm = (const float*)d_in[2];
    const float* w_uq     = (const float*)d_in[3];
    const float* w_dkv    = (const float*)d_in[4];
    const float* kv_a_nrm = (const float*)d_in[5];
    const float* w_ukv    = (const float*)d_in[6];
    const float* w_o      = (const float*)d_in[7];
    float* out = (float*)d_out;

    char* ws = (char*)d_ws;
    const size_t MB = 1024 * 1024;
    u16* xb    = (u16*)(ws);             // 16.8MB ; reused later as aob
    u16* wT1   = (u16*)(ws + 17 * MB);   // [2176][2048] dq^T + dkv^T(pad640) : 8.9MB
    u16* wTuq  = (u16*)(ws + 26 * MB);   // [3072][1536] : 9.4MB
    u16* wTukv = (u16*)(ws + 36 * MB);   // [4096][512]  : 4.2MB
    u16* wTo   = (u16*)(ws + 41 * MB);   // [2048][2048] : 8.4MB
    u16* C1    = (u16*)(ws + 50 * MB);   // [4096][2176] qlat|ckv|kpe : 17.8MB
    u16* qlb   = (u16*)(ws + 68 * MB);   // [4096][1536] : 12.6MB
    u16* qbuf  = (u16*)(ws + 81 * MB);   // [4096][3072] : 25.2MB
    u16* ckvnb = (u16*)(ws + 107 * MB);  // [4096][512]  : 4.2MB
    u16* kb    = (u16*)(ws + 112 * MB);  // [4096][16][192] : 25.2MB
    u16* vT    = (u16*)(ws + 138 * MB);  // [16][128][4096] : 16.8MB (ends 155MB)
    u16* aob   = xb;

    // 1. prep: x->bf16 + all weight transposes (one launch)
    prep_k<<<23296, 256, 0, stream>>>(x, xb, w_dq, w_dkv, w_uq, w_ukv, w_o,
                                      wT1, wTuq, wTukv, wTo);
    // 2. C1 = x @ [w_dq | w_dkv]  (N=2176), bf16 out
    gemm_mfma<1, 3><<<dim3(17, 32), 256, 0, stream>>>(xb, wT1, C1, nullptr, 2048, 2176);
    // 3. rmsnorm q latent + rmsnorm kv latent + rope k_pe (one launch)
    rms_all_k<<<8192, 256, 0, stream>>>(C1, q_a_norm, kv_a_nrm, qlb, ckvnb, kb);
    // 4. q = qlb @ w_uq with fused RoPE + attention scale, bf16 out
    gemm_mfma<2, 2><<<dim3(24, 32), 256, 0, stream>>>(qlb, wTuq, qbuf, nullptr, 1536, 3072);
    // 5. kv = ckvnb @ w_ukv -> k_nope into kb, V transposed into vT (coalesced)
    gemm_mfma<3, 2><<<dim3(32, 32), 256, 0, stream>>>(ckvnb, wTukv, kb, vT, 512, 4096);
    // 6. fused flash attention (512 blocks, 128-q tiles, balanced layering)
    attn_mfma<<<dim3(32, 16), 256, 0, stream>>>(qbuf, kb, vT, aob);
    // 7. out = aob @ w_o, fp32 out
    gemm_mfma<0, 3><<<dim3(16, 32), 256, 0, stream>>>(aob, wTo, out, nullptr, 2048, 2048);
}

// Round 8
// 436.218 us; speedup vs baseline: 1.3632x; 1.3632x over previous
//
#include <hip/hip_runtime.h>
#include <hip/hip_bf16.h>
#include <math.h>

#define SS 2048
#define HH 16
#define EPSF 1e-6f
#define MR 4096              // tokens
#define L2T 13.287712379549449f   // log2(10000)
// 1/sqrt(192) * log2(e), folded into q at the uq-GEMM epilogue
#define ASCL (0.07216878364870322f * 1.4426950408889634f)

typedef unsigned short u16;
typedef unsigned int u32;
typedef __attribute__((ext_vector_type(8))) short bf8_t;
typedef __attribute__((ext_vector_type(4))) float f4_t;

__device__ inline u16 f2b(float f) {
    __hip_bfloat16 h = __float2bfloat16(f);
    return __builtin_bit_cast(u16, h);
}
__device__ inline float b2f(u16 x) {
    u32 v = (u32)x << 16;
    return __builtin_bit_cast(float, v);
}

#define GLD16(g, l) __builtin_amdgcn_global_load_lds( \
    (const __attribute__((address_space(1))) u32*)(g), \
    (__attribute__((address_space(3))) u32*)(l), 16, 0, 0)

#define MFMA16(a,b,c) __builtin_amdgcn_mfma_f32_16x16x32_bf16((a),(b),(c),0,0,0)

// ================= prep: x->bf16 cvt + all 5 weight transposes =================
__global__ void prep_k(const float* __restrict__ x, u16* __restrict__ xb,
                       const float* __restrict__ w_dq, const float* __restrict__ w_dkv,
                       const float* __restrict__ w_uq, const float* __restrict__ w_ukv,
                       const float* __restrict__ w_o,
                       u16* __restrict__ wT1, u16* __restrict__ wTuq,
                       u16* __restrict__ wTukv, u16* __restrict__ wTo) {
    __shared__ float tt[32][33];
    int blk = blockIdx.x, tid = threadIdx.x;
    if (blk < 8192) {                       // x conversion: 4096x2048 fp32 -> bf16
        int i = blk * 256 + tid;
        float4 v = ((const float4*)x)[i];
        ushort4 o;
        o.x = f2b(v.x); o.y = f2b(v.y); o.z = f2b(v.z); o.w = f2b(v.w);
        *(ushort4*)(xb + (size_t)i * 4) = o;
        return;
    }
    blk -= 8192;
    const float* W; u16* dst; int K, N, Npad, nx;
    if (blk < 3072)       { W = w_dq;  dst = wT1;                      K = 2048; N = 1536; Npad = 1536; nx = 48; }
    else if (blk < 4352)  { blk -= 3072; W = w_dkv; dst = wT1 + (size_t)1536 * 2048; K = 2048; N = 576;  Npad = 640;  nx = 20; }
    else if (blk < 8960)  { blk -= 4352; W = w_uq;  dst = wTuq;        K = 1536; N = 3072; Npad = 3072; nx = 96; }
    else if (blk < 11008) { blk -= 8960; W = w_ukv; dst = wTukv;       K = 512;  N = 4096; Npad = 4096; nx = 128; }
    else                  { blk -= 11008; W = w_o;  dst = wTo;         K = 2048; N = 2048; Npad = 2048; nx = 64; }
    int n0 = (blk % nx) * 32, k0 = (blk / nx) * 32;
    int tx = tid & 31, ty = tid >> 5;
    for (int i = ty; i < 32; i += 8) {
        int n = n0 + tx;
        tt[i][tx] = (n < N) ? W[(size_t)(k0 + i) * N + n] : 0.f;
    }
    __syncthreads();
    for (int i = ty; i < 32; i += 8) {
        int n = n0 + i;
        if (n < Npad) dst[(size_t)n * K + k0 + tx] = f2b(tt[tx][i]);
    }
}

// ================= MFMA GEMM (m97 structure), templated epilogue =================
// MODE 0: fp32 out; MODE 1: bf16 out; MODE 2: bf16 + fused RoPE + ASCL (q path);
// MODE 3: kv path -> k_nope into kb[tok][16][192], V transposed into vT[16][128][4096]
template <int MODE, int MINW>
__global__ __launch_bounds__(256, MINW)
void gemm_mfma(const u16* __restrict__ A, const u16* __restrict__ BT,
               void* __restrict__ Cv, void* __restrict__ Cv2, int K, int N) {
    __shared__ u16 lA[128 * 32];
    __shared__ u16 lB[128 * 32];
    const int tid = threadIdx.x;
    const int w = tid >> 6, lane = tid & 63;
    const int quad = lane >> 4, col = lane & 15;
    const int wm = (w >> 1) * 64, wn = (w & 1) * 64;
    const int bm = blockIdx.y * 128, bn = blockIdx.x * 128;
    const int srow = lane >> 2;
    const int scol = (lane & 3) * 8;
    f4_t acc[4][4] = {};
    for (int k0 = 0; k0 < K; k0 += 32) {
        __syncthreads();
        #pragma unroll
        for (int cc = 0; cc < 2; cc++) {
            int c = 2 * w + cc;
            int row = c * 16 + srow;
            GLD16(A  + (size_t)(bm + row) * K + k0 + scol, (char*)lA + c * 1024);
            GLD16(BT + (size_t)(bn + row) * K + k0 + scol, (char*)lB + c * 1024);
        }
        __syncthreads();
        bf8_t af[4], bf[4];
        #pragma unroll
        for (int i = 0; i < 4; i++) {
            af[i] = *(const bf8_t*)(lA + (wm + i * 16 + col) * 32 + quad * 8);
            bf[i] = *(const bf8_t*)(lB + (wn + i * 16 + col) * 32 + quad * 8);
        }
        #pragma unroll
        for (int mi = 0; mi < 4; mi++)
            #pragma unroll
            for (int ni = 0; ni < 4; ni++)
                acc[mi][ni] = MFMA16(af[mi], bf[ni], acc[mi][ni]);
    }
    if constexpr (MODE == 0) {
        float* C = (float*)Cv;
        #pragma unroll
        for (int mi = 0; mi < 4; mi++)
            #pragma unroll
            for (int ni = 0; ni < 4; ni++) {
                int n = bn + wn + ni * 16 + col;
                #pragma unroll
                for (int r = 0; r < 4; r++) {
                    int m = bm + wm + mi * 16 + quad * 4 + r;
                    C[(size_t)m * N + n] = acc[mi][ni][r];
                }
            }
    } else if constexpr (MODE == 1) {
        u16* C = (u16*)Cv;
        #pragma unroll
        for (int mi = 0; mi < 4; mi++)
            #pragma unroll
            for (int ni = 0; ni < 4; ni++) {
                int n = bn + wn + ni * 16 + col;
                #pragma unroll
                for (int r = 0; r < 4; r++) {
                    int m = bm + wm + mi * 16 + quad * 4 + r;
                    C[(size_t)m * N + n] = f2b(acc[mi][ni][r]);
                }
            }
    } else if constexpr (MODE == 2) {
        u16* C = (u16*)Cv;
        int span = ((bn + wn) >> 6) % 3;      // 0,1: nope span; 2: pe span (64-aligned)
        if (span < 2) {
            #pragma unroll
            for (int mi = 0; mi < 4; mi++)
                #pragma unroll
                for (int ni = 0; ni < 4; ni++) {
                    int n = bn + wn + ni * 16 + col;
                    #pragma unroll
                    for (int r = 0; r < 4; r++) {
                        int m = bm + wm + mi * 16 + quad * 4 + r;
                        C[(size_t)m * N + n] = f2b(acc[mi][ni][r] * ASCL);
                    }
                }
        } else {
            #pragma unroll
            for (int ni = 0; ni < 2; ni++) {
                int e = ni * 16 + col;        // rope dim 0..31
                float inv = exp2f(-(float)e * (L2T / 32.0f));
                #pragma unroll
                for (int mi = 0; mi < 4; mi++) {
                    #pragma unroll
                    for (int r = 0; r < 4; r++) {
                        int m = bm + wm + mi * 16 + quad * 4 + r;
                        int pos = m & (SS - 1);
                        float ang = (float)pos * inv;
                        float cs, sn; sincosf(ang, &sn, &cs);
                        float x1 = acc[mi][ni][r], x2 = acc[mi][ni + 2][r];
                        int n = bn + wn + ni * 16 + col;
                        C[(size_t)m * N + n]      = f2b((x1 * cs - x2 * sn) * ASCL);
                        C[(size_t)m * N + n + 32] = f2b((x2 * cs + x1 * sn) * ASCL);
                    }
                }
            }
        }
    } else { // MODE 3
        u16* kb = (u16*)Cv;
        u16* vT = (u16*)Cv2;
        int h = blockIdx.x >> 1;
        if ((blockIdx.x & 1) == 0) {
            // k_nope block: col index = wn + ni*16 + col (0..127)
            #pragma unroll
            for (int ni = 0; ni < 4; ni++) {
                int cb = wn + ni * 16;
                #pragma unroll
                for (int mi = 0; mi < 4; mi++)
                    #pragma unroll
                    for (int r = 0; r < 4; r++) {
                        int m = bm + wm + mi * 16 + quad * 4 + r;
                        kb[((size_t)m * HH + h) * 192 + cb + col] = f2b(acc[mi][ni][r]);
                    }
            }
        } else {
            // V block: transpose 64x64 per wave in LDS, store coalesced along tok
            __shared__ u16 sc[4][64][72];
            u16 (*scw)[72] = sc[w];
            #pragma unroll
            for (int ni = 0; ni < 4; ni++) {
                int dvl = ni * 16 + col;
                #pragma unroll
                for (int mi = 0; mi < 4; mi++) {
                    ushort4 o;
                    o.x = f2b(acc[mi][ni][0]);
                    o.y = f2b(acc[mi][ni][1]);
                    o.z = f2b(acc[mi][ni][2]);
                    o.w = f2b(acc[mi][ni][3]);
                    *(ushort4*)&scw[dvl][mi * 16 + quad * 4] = o;
                }
            }
            // wave-private: no barrier needed, compiler inserts lgkmcnt waits
            #pragma unroll
            for (int cc = 0; cc < 8; cc++) {
                int dvl = cc * 8 + (lane >> 3);
                int t8 = lane & 7;
                bf8_t vv = *(const bf8_t*)&scw[dvl][t8 * 8];
                *(bf8_t*)(vT + ((size_t)(h * 128 + wn + dvl)) * 4096 + bm + wm + t8 * 8) = vv;
            }
        }
    }
}

// ===== merged rmsnorm: blocks 0..4095 -> q latent; 4096..8191 -> kv latent + rope k_pe =====
__global__ void rms_all_k(const u16* __restrict__ C1, const float* __restrict__ wq,
                          const float* __restrict__ wkv,
                          u16* __restrict__ qlb, u16* __restrict__ ckvnb,
                          u16* __restrict__ kb) {
    __shared__ float red[256];
    int tid = threadIdx.x;
    if (blockIdx.x < 4096) {
        int row = blockIdx.x;
        const ushort4* rp = (const ushort4*)(C1 + (size_t)row * 2176);
        float s = 0.f;
        for (int i = tid; i < 384; i += 256) {
            ushort4 u = rp[i];
            float a = b2f(u.x), b = b2f(u.y), c = b2f(u.z), d = b2f(u.w);
            s += a * a + b * b + c * c + d * d;
        }
        red[tid] = s;
        __syncthreads();
        for (int off = 128; off > 0; off >>= 1) {
            if (tid < off) red[tid] += red[tid + off];
            __syncthreads();
        }
        float sc = rsqrtf(red[0] * (1.0f / 1536.0f) + EPSF);
        ushort4* op = (ushort4*)(qlb + (size_t)row * 1536);
        const float4* wv = (const float4*)wq;
        for (int i = tid; i < 384; i += 256) {
            ushort4 u = rp[i];
            float4 ww = wv[i];
            ushort4 o;
            o.x = f2b(b2f(u.x) * sc * ww.x);
            o.y = f2b(b2f(u.y) * sc * ww.y);
            o.z = f2b(b2f(u.z) * sc * ww.z);
            o.w = f2b(b2f(u.w) * sc * ww.w);
            op[i] = o;
        }
    } else {
        int row = blockIdx.x - 4096;
        const u16* base = C1 + (size_t)row * 2176 + 1536;
        if (tid < 32) {   // rope k_pe -> broadcast into kb[row][h][128..192]
            int t = tid;
            float x1 = b2f(base[512 + t]), x2 = b2f(base[544 + t]);
            int pos = row & (SS - 1);
            float inv = exp2f(-(float)t * (L2T / 32.0f));
            float ang = (float)pos * inv;
            float cs, sn; sincosf(ang, &sn, &cs);
            u16 y1 = f2b(x1 * cs - x2 * sn);
            u16 y2 = f2b(x2 * cs + x1 * sn);
            u16* kr = kb + (size_t)row * HH * 192;
            #pragma unroll
            for (int h = 0; h < HH; h++) {
                kr[h * 192 + 128 + t] = y1;
                kr[h * 192 + 160 + t] = y2;
            }
        }
        const ushort4* rp = (const ushort4*)base;
        float s = 0.f;
        if (tid < 128) {
            ushort4 u = rp[tid];
            float a = b2f(u.x), b = b2f(u.y), c = b2f(u.z), d = b2f(u.w);
            s = a * a + b * b + c * c + d * d;
        }
        red[tid] = s;
        __syncthreads();
        for (int off = 128; off > 0; off >>= 1) {
            if (tid < off) red[tid] += red[tid + off];
            __syncthreads();
        }
        float sc = rsqrtf(red[0] * (1.0f / 512.0f) + EPSF);
        if (tid < 128) {
            ushort4 u = rp[tid];
            float4 ww = ((const float4*)wkv)[tid];
            ushort4 o;
            o.x = f2b(b2f(u.x) * sc * ww.x);
            o.y = f2b(b2f(u.y) * sc * ww.y);
            o.z = f2b(b2f(u.z) * sc * ww.z);
            o.w = f2b(b2f(u.w) * sc * ww.w);
            ((ushort4*)(ckvnb + (size_t)row * 512))[tid] = o;
        }
    }
}

// ================= Fused flash attention (8 waves, Q-tile 128, 16 q/wave) =================
// grid (32 bh, 16), block 512 = 8 waves. Q-tile 128/block; K/V staged once per 128 q.
// Deferred softmax: logits are pre-scaled log2-space (ASCL upstream); p = exp2(s-8)
// (uniform 2^-8 cancels in O/l), no running max, l-butterfly once at the end.
// kb [tok][16][192]; vT [16][128][4096]. Registers stay at round-6 levels (16 q/wave).
__global__ __launch_bounds__(512, 4)
void attn_mfma(const u16* __restrict__ qb, const u16* __restrict__ kb,
               const u16* __restrict__ vT, u16* __restrict__ ob) {
    __shared__ u16 lK[64 * 200];     // [key][192+pad], 400B rows: 25 KB
    __shared__ u16 lV[128 * 72];     // V^T [dv][key(64)+pad], 144B rows: 18 KB
    __shared__ u16 lP[8 * 16 * 72];  // per-wave P [16 q][64 key+pad]: 18 KB
    const int tid = threadIdx.x, w = tid >> 6, lane = tid & 63;
    const int quad = lane >> 4, col = lane & 15;
    const int bh = blockIdx.x, b = bh >> 4, h = bh & 15;
    const int y = blockIdx.y;
    const int qt = (y < 8) ? (15 - y) : (y - 8);   // long layer first, short backfills
    const int tok0 = b * SS;
    // per-lane staging offsets: chunks c=w+8*jj; c<25 -> K (400B rows), 25..42 -> V (144B rows)
    int goff[6];
    #pragma unroll
    for (int jj = 0; jj < 6; jj++) {
        int c = w + 8 * jj;
        if (c < 25) {
            int o = c * 1024 + lane * 16;
            int row = o / 400, ro = o - row * 400;
            goff[jj] = (ro < 384) ? (row * HH + h) * 192 + (ro >> 1) : 0;
        } else {
            int c2 = c - 25;
            int o = c2 * 1024 + lane * 16;
            int row = o / 144, ro = o - row * 144;
            goff[jj] = (ro < 128) ? (h * 128 + row) * 4096 + (ro >> 1) : 0;
        }
    }
    u16* pw = lP + w * 16 * 72;
    const int qb_w = qt * 128 + w * 16;   // local q base for this wave's 16 queries
    bf8_t qf[6];
    {
        int qtok = tok0 + qb_w + col;
        const u16* qp = qb + ((size_t)qtok * HH + h) * 192 + quad * 8;
        #pragma unroll
        for (int kc = 0; kc < 6; kc++) qf[kc] = *(const bf8_t*)(qp + kc * 32);
    }
    f4_t o[8] = {};
    float lrow[4] = {0.f, 0.f, 0.f, 0.f};

    const int nkt = 2 * qt + 2;
    for (int kt = 0; kt < nkt; kt++) {
        const int kt64 = kt * 64;
        size_t kbase = (size_t)(tok0 + kt64) * (HH * 192);
        size_t vbase = (size_t)(tok0 + kt64);
        __syncthreads();
        #pragma unroll
        for (int jj = 0; jj < 6; jj++) {
            int c = w + 8 * jj;
            if (c < 25)      GLD16(kb + kbase + goff[jj], (char*)lK + c * 1024);
            else if (c < 43) GLD16(vT + vbase + goff[jj], (char*)lV + (c - 25) * 1024);
        }
        __syncthreads();    // vmcnt(0) drain: K+V landed
        if (kt64 > qb_w) continue;   // wave idle this iter (no barrier below)
        // S = Q K^T per t-tile; diagonal tile masked; beyond-diag tiles -> P=0
        #pragma unroll
        for (int t = 0; t < 4; t++) {
            int kb_l = kt64 + t * 16;
            if (kb_l <= qb_w) {
                f4_t s = {};
                #pragma unroll
                for (int kc = 0; kc < 6; kc++) {
                    bf8_t kf = *(const bf8_t*)(lK + (t * 16 + col) * 200 + kc * 32 + quad * 8);
                    s = MFMA16(qf[kc], kf, s);
                }
                if (kb_l == qb_w) {      // diagonal 16x16: causal mask
                    int kg = col;
                    #pragma unroll
                    for (int r = 0; r < 4; r++)
                        if (kg > quad * 4 + r) s[r] = -1e30f;
                }
                #pragma unroll
                for (int r = 0; r < 4; r++) {
                    float p = exp2f(s[r] - 8.0f);
                    lrow[r] += p;
                    pw[(quad * 4 + r) * 72 + t * 16 + col] = f2b(p);
                }
            } else {
                #pragma unroll
                for (int r = 0; r < 4; r++)
                    pw[(quad * 4 + r) * 72 + t * 16 + col] = 0;
            }
        }
        // O += P V  (P wave-private round-trip; V B-frags from LDS)
        #pragma unroll
        for (int kc2 = 0; kc2 < 2; kc2++) {
            bf8_t pf = *(const bf8_t*)(pw + col * 72 + kc2 * 32 + quad * 8);
            #pragma unroll
            for (int n = 0; n < 8; n++) {
                bf8_t vf = *(const bf8_t*)(lV + (n * 16 + col) * 72 + kc2 * 32 + quad * 8);
                o[n] = MFMA16(pf, vf, o[n]);
            }
        }
    }
    // single deferred l reduction across the 16 col-lanes
    #pragma unroll
    for (int off = 1; off < 16; off <<= 1)
        #pragma unroll
        for (int r = 0; r < 4; r++) lrow[r] += __shfl_xor(lrow[r], off);
    float linv[4];
    #pragma unroll
    for (int r = 0; r < 4; r++) linv[r] = 1.0f / lrow[r];
    #pragma unroll
    for (int n = 0; n < 8; n++)
        #pragma unroll
        for (int r = 0; r < 4; r++) {
            int qtok = tok0 + qb_w + quad * 4 + r;
            ob[((size_t)qtok * HH + h) * 128 + n * 16 + col] = f2b(o[n][r] * linv[r]);
        }
}

extern "C" void kernel_launch(void* const* d_in, const int* in_sizes, int n_in,
                              void* d_out, int out_size, void* d_ws, size_t ws_size,
                              hipStream_t stream) {
    const float* x        = (const float*)d_in[0];
    const float* w_dq     = (const float*)d_in[1];
    const float* q_a_norm = (const float*)d_in[2];
    const float* w_uq     = (const float*)d_in[3];
    const float* w_dkv    = (const float*)d_in[4];
    const float* kv_a_nrm = (const float*)d_in[5];
    const float* w_ukv    = (const float*)d_in[6];
    const float* w_o      = (const float*)d_in[7];
    float* out = (float*)d_out;

    char* ws = (char*)d_ws;
    const size_t MB = 1024 * 1024;
    u16* xb    = (u16*)(ws);             // 16.8MB ; reused later as aob
    u16* wT1   = (u16*)(ws + 17 * MB);   // [2176][2048] dq^T + dkv^T(pad640) : 8.9MB
    u16* wTuq  = (u16*)(ws + 26 * MB);   // [3072][1536] : 9.4MB
    u16* wTukv = (u16*)(ws + 36 * MB);   // [4096][512]  : 4.2MB
    u16* wTo   = (u16*)(ws + 41 * MB);   // [2048][2048] : 8.4MB
    u16* C1    = (u16*)(ws + 50 * MB);   // [4096][2176] qlat|ckv|kpe : 17.8MB
    u16* qlb   = (u16*)(ws + 68 * MB);   // [4096][1536] : 12.6MB
    u16* qbuf  = (u16*)(ws + 81 * MB);   // [4096][3072] : 25.2MB
    u16* ckvnb = (u16*)(ws + 107 * MB);  // [4096][512]  : 4.2MB
    u16* kb    = (u16*)(ws + 112 * MB);  // [4096][16][192] : 25.2MB
    u16* vT    = (u16*)(ws + 138 * MB);  // [16][128][4096] : 16.8MB (ends 155MB)
    u16* aob   = xb;

    // 1. prep: x->bf16 + all weight transposes (one launch)
    prep_k<<<23296, 256, 0, stream>>>(x, xb, w_dq, w_dkv, w_uq, w_ukv, w_o,
                                      wT1, wTuq, wTukv, wTo);
    // 2. C1 = x @ [w_dq | w_dkv]  (N=2176), bf16 out
    gemm_mfma<1, 3><<<dim3(17, 32), 256, 0, stream>>>(xb, wT1, C1, nullptr, 2048, 2176);
    // 3. rmsnorm q latent + rmsnorm kv latent + rope k_pe (one launch)
    rms_all_k<<<8192, 256, 0, stream>>>(C1, q_a_norm, kv_a_nrm, qlb, ckvnb, kb);
    // 4. q = qlb @ w_uq with fused RoPE + attention scale, bf16 out
    gemm_mfma<2, 2><<<dim3(24, 32), 256, 0, stream>>>(qlb, wTuq, qbuf, nullptr, 1536, 3072);
    // 5. kv = ckvnb @ w_ukv -> k_nope into kb, V transposed into vT (coalesced)
    gemm_mfma<3, 2><<<dim3(32, 32), 256, 0, stream>>>(ckvnb, wTukv, kb, vT, 512, 4096);
    // 6. fused flash attention (512 blocks x 512 thr, 128-q tiles, 2 blocks/CU)
    attn_mfma<<<dim3(32, 16), 512, 0, stream>>>(qbuf, kb, vT, aob);
    // 7. out = aob @ w_o, fp32 out
    gemm_mfma<0, 3><<<dim3(16, 32), 256, 0, stream>>>(aob, wTo, out, nullptr, 2048, 2048);
}